// Round 1
// baseline (698.495 us; speedup 1.0000x reference)
//
#include <hip/hip_runtime.h>

#define D 32

__global__ void init_kernel(const float* __restrict__ ue, const float* __restrict__ ie,
                            float* __restrict__ e, float* __restrict__ acc,
                            int nu_elems, int total) {
    int stride = gridDim.x * blockDim.x;
    for (int i = blockIdx.x * blockDim.x + threadIdx.x; i < total; i += stride) {
        float v = (i < nu_elems) ? ue[i] : ie[i - nu_elems];
        e[i] = v;
        acc[i] = v;
    }
}

__global__ void zero_kernel(float* __restrict__ p, int n) {
    int stride = gridDim.x * blockDim.x;
    for (int i = blockIdx.x * blockDim.x + threadIdx.x; i < n; i += stride) p[i] = 0.0f;
}

// One thread per (edge, dim) pair. Lanes within a 32-group share an edge, so
// the e_old[c*D + d] gather is a coalesced 128B segment per edge.
__global__ void spmm_kernel(const int* __restrict__ row, const int* __restrict__ col,
                            const float* __restrict__ val, const float* __restrict__ eo,
                            float* __restrict__ en, int nnz) {
    int stride = gridDim.x * blockDim.x;
    int total = nnz * D;  // 64M < 2^31, fits int
    for (int i = blockIdx.x * blockDim.x + threadIdx.x; i < total; i += stride) {
        int edge = i >> 5;
        int d = i & 31;
        int r = row[edge];
        int c = col[edge];
        float v = val[edge];
        atomicAdd(&en[r * D + d], v * eo[c * D + d]);
    }
}

__global__ void add_kernel(float* __restrict__ acc, const float* __restrict__ e, int n) {
    int stride = gridDim.x * blockDim.x;
    for (int i = blockIdx.x * blockDim.x + threadIdx.x; i < n; i += stride) acc[i] += e[i];
}

__global__ void add_scale_kernel(float* __restrict__ acc, const float* __restrict__ e,
                                 float s, int n) {
    int stride = gridDim.x * blockDim.x;
    for (int i = blockIdx.x * blockDim.x + threadIdx.x; i < n; i += stride)
        acc[i] = (acc[i] + e[i]) * s;
}

extern "C" void kernel_launch(void* const* d_in, const int* in_sizes, int n_in,
                              void* d_out, int out_size, void* d_ws, size_t ws_size,
                              hipStream_t stream) {
    const float* ue  = (const float*)d_in[0];
    const float* ie  = (const float*)d_in[1];
    const int*   row = (const int*)d_in[2];
    const int*   col = (const int*)d_in[3];
    const float* val = (const float*)d_in[4];
    // d_in[5] is n_layers (device scalar) — fixed at 3 for this problem.

    const int nu_elems = in_sizes[0];          // 200000*32
    const int ni_elems = in_sizes[1];          // 100000*32
    const int nnz      = in_sizes[2];          // 2,000,000
    const int total    = nu_elems + ni_elems;  // == out_size = 9.6M

    float* acc = (float*)d_out;
    float* e0  = (float*)d_ws;
    float* e1  = e0 + (size_t)total;

    const int blk = 256;
    int g_elem = (total + blk - 1) / blk;
    if (g_elem > 2048) g_elem = 2048;
    int total_pairs = nnz * D;
    int g_spmm = (total_pairs + blk - 1) / blk;
    if (g_spmm > 32768) g_spmm = 32768;

    // e0 = concat(user_emb, item_emb); acc = e0
    init_kernel<<<g_elem, blk, 0, stream>>>(ue, ie, e0, acc, nu_elems, total);

    // layer 1: e1 = L @ e0; acc += e1
    zero_kernel<<<g_elem, blk, 0, stream>>>(e1, total);
    spmm_kernel<<<g_spmm, blk, 0, stream>>>(row, col, val, e0, e1, nnz);
    add_kernel<<<g_elem, blk, 0, stream>>>(acc, e1, total);

    // layer 2: e0 = L @ e1; acc += e0
    zero_kernel<<<g_elem, blk, 0, stream>>>(e0, total);
    spmm_kernel<<<g_spmm, blk, 0, stream>>>(row, col, val, e1, e0, nnz);
    add_kernel<<<g_elem, blk, 0, stream>>>(acc, e0, total);

    // layer 3: e1 = L @ e0; acc = (acc + e1) / 4
    zero_kernel<<<g_elem, blk, 0, stream>>>(e1, total);
    spmm_kernel<<<g_spmm, blk, 0, stream>>>(row, col, val, e0, e1, nnz);
    add_scale_kernel<<<g_elem, blk, 0, stream>>>(acc, e1, 0.25f, total);
}

// Round 2
// 634.563 us; speedup vs baseline: 1.1007x; 1.1007x over previous
//
#include <hip/hip_runtime.h>

#define D 32
#define SCAN_TPB 256
#define SCAN_EPT 4
#define SCAN_ELEMS (SCAN_TPB * SCAN_EPT)  // 1024

__global__ void init_kernel(const float* __restrict__ ue, const float* __restrict__ ie,
                            float* __restrict__ e, float* __restrict__ acc,
                            int nu_elems, int total) {
    int stride = gridDim.x * blockDim.x;
    for (int i = blockIdx.x * blockDim.x + threadIdx.x; i < total; i += stride) {
        float v = (i < nu_elems) ? ue[i] : ie[i - nu_elems];
        e[i] = v;
        acc[i] = v;
    }
}

__global__ void zero_int_kernel(int* __restrict__ p, int n) {
    int stride = gridDim.x * blockDim.x;
    for (int i = blockIdx.x * blockDim.x + threadIdx.x; i < n; i += stride) p[i] = 0;
}

__global__ void hist_kernel(const int* __restrict__ row, int* __restrict__ cnt, int nnz) {
    int stride = gridDim.x * blockDim.x;
    for (int i = blockIdx.x * blockDim.x + threadIdx.x; i < nnz; i += stride)
        atomicAdd(&cnt[row[i]], 1);
}

// Block-level exclusive scan: each block scans SCAN_ELEMS elements of cnt into
// ptr (block-local exclusive), and writes the block total to bsum[blockIdx].
__global__ void scan1_kernel(const int* __restrict__ cnt, int* __restrict__ ptr,
                             int* __restrict__ bsum, int n) {
    __shared__ int lds[SCAN_TPB];
    int base = blockIdx.x * SCAN_ELEMS + threadIdx.x * SCAN_EPT;
    int v[SCAN_EPT];
    int s = 0;
#pragma unroll
    for (int k = 0; k < SCAN_EPT; ++k) {
        v[k] = (base + k < n) ? cnt[base + k] : 0;
        s += v[k];
    }
    lds[threadIdx.x] = s;
    __syncthreads();
    for (int off = 1; off < SCAN_TPB; off <<= 1) {
        int x = lds[threadIdx.x];
        int y = (threadIdx.x >= off) ? lds[threadIdx.x - off] : 0;
        __syncthreads();
        lds[threadIdx.x] = x + y;
        __syncthreads();
    }
    int excl = lds[threadIdx.x] - s;  // exclusive prefix of this thread within block
    int run = excl;
#pragma unroll
    for (int k = 0; k < SCAN_EPT; ++k) {
        if (base + k < n) ptr[base + k] = run;
        run += v[k];
    }
    if (threadIdx.x == SCAN_TPB - 1) bsum[blockIdx.x] = lds[SCAN_TPB - 1];
}

// Single-block exclusive scan of the nb block sums (nb <= 512).
__global__ void scan2_kernel(const int* __restrict__ bsum, int* __restrict__ boff, int nb) {
    __shared__ int lds[512];
    int t = threadIdx.x;
    int s = (t < nb) ? bsum[t] : 0;
    lds[t] = s;
    __syncthreads();
    for (int off = 1; off < 512; off <<= 1) {
        int x = lds[t];
        int y = (t >= off) ? lds[t - off] : 0;
        __syncthreads();
        lds[t] = x + y;
        __syncthreads();
    }
    if (t < nb) boff[t] = lds[t] - s;  // exclusive
}

// Add block offsets; duplicate ptr into tmp (scatter cursors); set ptr[n]=nnz.
__global__ void scan3_kernel(int* __restrict__ ptr, int* __restrict__ tmp,
                             const int* __restrict__ boff, int n, int nnz) {
    int stride = gridDim.x * blockDim.x;
    for (int i = blockIdx.x * blockDim.x + threadIdx.x; i < n; i += stride) {
        int p = ptr[i] + boff[i / SCAN_ELEMS];
        ptr[i] = p;
        tmp[i] = p;
    }
    if (blockIdx.x == 0 && threadIdx.x == 0) ptr[n] = nnz;
}

__global__ void scatter_kernel(const int* __restrict__ row, const int* __restrict__ col,
                               const float* __restrict__ val, int* __restrict__ tmp,
                               int2* __restrict__ ce, int nnz) {
    int stride = gridDim.x * blockDim.x;
    for (int i = blockIdx.x * blockDim.x + threadIdx.x; i < nnz; i += stride) {
        int r = row[i];
        int pos = atomicAdd(&tmp[r], 1);
        ce[pos] = make_int2(col[i], __float_as_int(val[i]));
    }
}

// Gather-side SpMM, 32 threads per row (one per dim), fused acc update.
__global__ __launch_bounds__(256) void spmm_csr_kernel(
    const int* __restrict__ ptr, const int2* __restrict__ ce,
    const float* __restrict__ eo, float* __restrict__ en,
    float* __restrict__ acc, int n_nodes, int last) {
    int t = blockIdx.x * blockDim.x + threadIdx.x;
    int r = t >> 5;
    int d = t & 31;
    if (r >= n_nodes) return;
    int start = ptr[r];
    int end = ptr[r + 1];
    float s = 0.0f;
    for (int j = start; j < end; ++j) {
        int2 e = ce[j];  // broadcast load (same addr across the 32-lane group)
        s += __int_as_float(e.y) * eo[e.x * D + d];
    }
    int idx = r * D + d;
    if (last) {
        acc[idx] = (acc[idx] + s) * 0.25f;
    } else {
        en[idx] = s;
        acc[idx] += s;
    }
}

extern "C" void kernel_launch(void* const* d_in, const int* in_sizes, int n_in,
                              void* d_out, int out_size, void* d_ws, size_t ws_size,
                              hipStream_t stream) {
    const float* ue  = (const float*)d_in[0];
    const float* ie  = (const float*)d_in[1];
    const int*   row = (const int*)d_in[2];
    const int*   col = (const int*)d_in[3];
    const float* val = (const float*)d_in[4];

    const int nu_elems = in_sizes[0];          // 200000*32
    const int ni_elems = in_sizes[1];          // 100000*32
    const int nnz      = in_sizes[2];          // 2,000,000
    const int total    = nu_elems + ni_elems;  // 9.6M
    const int n_nodes  = total / D;            // 300,000

    float* acc = (float*)d_out;

    // Workspace layout (all 8B-aligned: element counts are even):
    char* ws = (char*)d_ws;
    float* e0 = (float*)ws;                       ws += (size_t)total * 4;
    float* e1 = (float*)ws;                       ws += (size_t)total * 4;
    int2*  ce = (int2*)ws;                        ws += (size_t)nnz * 8;
    int*  cnt = (int*)ws;                         ws += (size_t)n_nodes * 4;
    int*  ptr = (int*)ws;                         ws += (size_t)(n_nodes + 2) * 4;
    int*  tmp = (int*)ws;                         ws += (size_t)n_nodes * 4;
    int* bsum = (int*)ws;                         ws += 4096;
    int* boff = (int*)ws;

    const int blk = 256;
    int g_elem = (total + blk - 1) / blk;
    if (g_elem > 2048) g_elem = 2048;
    int g_edge = (nnz + blk - 1) / blk;
    if (g_edge > 4096) g_edge = 4096;
    int g_node = (n_nodes + blk - 1) / blk;
    if (g_node > 2048) g_node = 2048;
    int nb_scan = (n_nodes + SCAN_ELEMS - 1) / SCAN_ELEMS;  // 293 for 300K
    int g_spmm = (n_nodes * D + blk - 1) / blk;             // 37500

    // e0 = concat(user_emb, item_emb); acc = e0
    init_kernel<<<g_elem, blk, 0, stream>>>(ue, ie, e0, acc, nu_elems, total);

    // Build CSR
    zero_int_kernel<<<g_node, blk, 0, stream>>>(cnt, n_nodes);
    hist_kernel<<<g_edge, blk, 0, stream>>>(row, cnt, nnz);
    scan1_kernel<<<nb_scan, SCAN_TPB, 0, stream>>>(cnt, ptr, bsum, n_nodes);
    scan2_kernel<<<1, 512, 0, stream>>>(bsum, boff, nb_scan);
    scan3_kernel<<<g_node, blk, 0, stream>>>(ptr, tmp, boff, n_nodes, nnz);
    scatter_kernel<<<g_edge, blk, 0, stream>>>(row, col, val, tmp, ce, nnz);

    // 3 layers, fused acc update (layer 3 also applies the /4 scale)
    spmm_csr_kernel<<<g_spmm, blk, 0, stream>>>(ptr, ce, e0, e1, acc, n_nodes, 0);
    spmm_csr_kernel<<<g_spmm, blk, 0, stream>>>(ptr, ce, e1, e0, acc, n_nodes, 0);
    spmm_csr_kernel<<<g_spmm, blk, 0, stream>>>(ptr, ce, e0, e1, acc, n_nodes, 1);
}